// Round 1
// baseline (618.699 us; speedup 1.0000x reference)
//
#include <hip/hip_runtime.h>

#define H_DIM 2048
#define DMID  1024
#define DOUT  256
#define NTOK  32768
#define NIMG  32

typedef __attribute__((ext_vector_type(8))) __bf16 bf16x8;
typedef __attribute__((ext_vector_type(4))) float f32x4;

__device__ __forceinline__ unsigned f2bf(float f) {
  unsigned u = __builtin_bit_cast(unsigned, f);
  u += 0x7fff + ((u >> 16) & 1);   // RNE
  return u >> 16;
}

// async global->LDS, 16B per lane. LDS dest must be wave-uniform base + lane*16.
__device__ __forceinline__ void async_copy16(const void* gptr, void* lptr) {
  auto g = (const __attribute__((address_space(1))) unsigned int*)(unsigned long long)gptr;
  unsigned loff = (unsigned)(unsigned long long)lptr;
  auto l = (__attribute__((address_space(3))) unsigned int*)loff;
  __builtin_amdgcn_global_load_lds(g, l, 16, 0, 0);
}

__global__ void convert_f32_bf16(const float* __restrict__ src,
                                 unsigned short* __restrict__ dst, int n4) {
  int i = blockIdx.x * blockDim.x + threadIdx.x;
  if (i >= n4) return;
  float4 f = ((const float4*)src)[i];
  ushort4 o;
  o.x = (unsigned short)f2bf(f.x);
  o.y = (unsigned short)f2bf(f.y);
  o.z = (unsigned short)f2bf(f.z);
  o.w = (unsigned short)f2bf(f.w);
  ((ushort4*)dst)[i] = o;
}

// One block per token row: gather via flat_idx + fp32->bf16. 8 elems/thread.
__global__ __launch_bounds__(256) void gather_convert_A(
    const float* __restrict__ hidden, const int* __restrict__ flat_idx,
    unsigned short* __restrict__ Abuf) {
  int row = blockIdx.x;
  int src_row = flat_idx[row];
  const float* src = hidden + (size_t)src_row * H_DIM + threadIdx.x * 8;
  float4 fa = *(const float4*)src;
  float4 fb = *(const float4*)(src + 4);
  uint4 pk;
  pk.x = (f2bf(fa.y) << 16) | f2bf(fa.x);
  pk.y = (f2bf(fa.w) << 16) | f2bf(fa.z);
  pk.z = (f2bf(fb.y) << 16) | f2bf(fb.x);
  pk.w = (f2bf(fb.w) << 16) | f2bf(fb.z);
  *(uint4*)(Abuf + (size_t)row * H_DIM + threadIdx.x * 8) = pk;
}

// C[m,n] = mish(sum_k A[m,k]*W1[n,k] + b1[n]) -> bf16 h
// PRE=true: A pre-gathered bf16 (full async path). PRE=false: fp32 + inline cvt.
// 1-D grid of 2048 blocks, XCD-clustered swizzle: the 8 n-blocks sharing one
// A m-panel are consecutive bids on ONE XCD (bid%8 == XCD round-robin), so the
// A panel is fetched into that XCD's L2 once and hit 7 times instead of being
// pulled by 8 different XCDs (which cost 4x beyond-L2 over-fetch: 532MB vs 132MB).
template <bool PRE>
__global__ __launch_bounds__(256) void gemm1_mish(
    const float* __restrict__ A32, const unsigned short* __restrict__ Abf,
    const unsigned short* __restrict__ B, const float* __restrict__ b1,
    const int* __restrict__ flat_idx, unsigned short* __restrict__ Hout) {
  __shared__ __align__(16) unsigned short As[128 * 64];
  __shared__ __align__(16) unsigned short Bs[128 * 64];
  __shared__ int rowmap[128];

  const int tid = threadIdx.x;
  const int lane = tid & 63;
  const int wave = tid >> 6;
  const int wm = wave >> 1, wn = wave & 1;
  // XCD-clustered decomposition: x = XCD slot, j = per-XCD sequence.
  // m-panel = x*32 + (j>>3)  (each XCD owns 32 contiguous m-panels)
  // n-block = j&7            (8 siblings adjacent in dispatch order)
  const int bid = blockIdx.x;
  const int xcd = bid & 7;
  const int j = bid >> 3;
  const int m0 = (xcd * 32 + (j >> 3)) * 128;
  const int n0 = (j & 7) * 128;

  if constexpr (!PRE) {
    if (tid < 128) rowmap[tid] = flat_idx[m0 + tid];
    __syncthreads();
  }

  f32x4 acc[4][4];
#pragma unroll
  for (int i = 0; i < 4; i++)
#pragma unroll
    for (int jj = 0; jj < 4; jj++) acc[i][jj] = f32x4{0.f, 0.f, 0.f, 0.f};

  for (int kk = 0; kk < H_DIM; kk += 64) {
#pragma unroll
    for (int it = 0; it < 4; ++it) {
      int id = it * 256 + tid;
      int row = id >> 3, c8 = id & 7;
      int gc8 = c8 ^ (row & 7);
      async_copy16(B + (size_t)(n0 + row) * H_DIM + kk + gc8 * 8, &Bs[id * 8]);
    }
    if constexpr (PRE) {
#pragma unroll
      for (int it = 0; it < 4; ++it) {
        int id = it * 256 + tid;
        int row = id >> 3, c8 = id & 7;
        int gc8 = c8 ^ (row & 7);
        async_copy16(Abf + (size_t)(m0 + row) * H_DIM + kk + gc8 * 8, &As[id * 8]);
      }
    } else {
#pragma unroll
      for (int it = 0; it < 4; ++it) {
        int id = it * 256 + tid;
        int row = id >> 3, c8 = id & 7;
        int gc8 = c8 ^ (row & 7);
        const float* src = A32 + (size_t)rowmap[row] * H_DIM + kk + gc8 * 8;
        float4 fa = *(const float4*)src;
        float4 fb = *(const float4*)(src + 4);
        uint4 pk;
        pk.x = (f2bf(fa.y) << 16) | f2bf(fa.x);
        pk.y = (f2bf(fa.w) << 16) | f2bf(fa.z);
        pk.z = (f2bf(fb.y) << 16) | f2bf(fb.x);
        pk.w = (f2bf(fb.w) << 16) | f2bf(fb.z);
        *(uint4*)&As[id * 8] = pk;
      }
    }
    __syncthreads();
#pragma unroll
    for (int ks = 0; ks < 2; ++ks) {
      bf16x8 af[4], bg[4];
#pragma unroll
      for (int mt = 0; mt < 4; ++mt) {
        int r = wm * 64 + mt * 16 + (lane & 15);
        int jj = (lane >> 4) + ks * 4;
        af[mt] = *(const bf16x8*)&As[r * 64 + ((jj ^ (r & 7)) << 3)];
      }
#pragma unroll
      for (int nt = 0; nt < 4; ++nt) {
        int r = wn * 64 + nt * 16 + (lane & 15);
        int jj = (lane >> 4) + ks * 4;
        bg[nt] = *(const bf16x8*)&Bs[r * 64 + ((jj ^ (r & 7)) << 3)];
      }
#pragma unroll
      for (int mt = 0; mt < 4; ++mt)
#pragma unroll
        for (int nt = 0; nt < 4; ++nt)
          acc[mt][nt] = __builtin_amdgcn_mfma_f32_16x16x32_bf16(
              af[mt], bg[nt], acc[mt][nt], 0, 0, 0);
    }
    __syncthreads();
  }

#pragma unroll
  for (int nt = 0; nt < 4; ++nt) {
    int gc = n0 + wn * 64 + nt * 16 + (lane & 15);
    float bias = b1[gc];
#pragma unroll
    for (int mt = 0; mt < 4; ++mt) {
#pragma unroll
      for (int r = 0; r < 4; ++r) {
        int grow = m0 + wm * 64 + mt * 16 + ((lane >> 4) << 2) + r;
        float x = acc[mt][nt][r] + bias;
        // mish(x) = x*tanh(softplus(x)) = x*u/(u+2), u = t(t+2), t = e^x
        float t = __expf(x);
        float u = t * (t + 2.f);
        float y = (x < 10.f) ? x * u * __builtin_amdgcn_rcpf(u + 2.f) : x;
        Hout[(size_t)grow * DMID + gc] = (unsigned short)f2bf(y);
      }
    }
  }
}

// out[seg[m], n] += sum_k h[m,k]*W2[n,k] + b2[n]
// 1-D grid of 512 blocks, same XCD-clustered swizzle (2 n-blocks per m-panel).
__global__ __launch_bounds__(256) void gemm2_pool(
    const unsigned short* __restrict__ Hin, const unsigned short* __restrict__ W2b,
    const float* __restrict__ b2, const int* __restrict__ seg,
    float* __restrict__ out) {
  __shared__ __align__(16) unsigned short As[128 * 64];
  __shared__ __align__(16) unsigned short Bs[128 * 64];
  __shared__ int segl[128];

  const int tid = threadIdx.x;
  const int lane = tid & 63;
  const int wave = tid >> 6;
  const int wm = wave >> 1, wn = wave & 1;
  const int bid = blockIdx.x;
  const int xcd = bid & 7;
  const int j = bid >> 3;
  const int m0 = (xcd * 32 + (j >> 1)) * 128;
  const int n0 = (j & 1) * 128;

  if (tid < 128) segl[tid] = seg[m0 + tid];
  __syncthreads();

  f32x4 acc[4][4];
#pragma unroll
  for (int i = 0; i < 4; i++)
#pragma unroll
    for (int jj = 0; jj < 4; jj++) acc[i][jj] = f32x4{0.f, 0.f, 0.f, 0.f};

  for (int kk = 0; kk < DMID; kk += 64) {
#pragma unroll
    for (int it = 0; it < 4; ++it) {
      int id = it * 256 + tid;
      int row = id >> 3, c8 = id & 7;
      int gc8 = c8 ^ (row & 7);
      async_copy16(Hin + (size_t)(m0 + row) * DMID + kk + gc8 * 8, &As[id * 8]);
      async_copy16(W2b + (size_t)(n0 + row) * DMID + kk + gc8 * 8, &Bs[id * 8]);
    }
    __syncthreads();
#pragma unroll
    for (int ks = 0; ks < 2; ++ks) {
      bf16x8 af[4], bg[4];
#pragma unroll
      for (int mt = 0; mt < 4; ++mt) {
        int r = wm * 64 + mt * 16 + (lane & 15);
        int jj = (lane >> 4) + ks * 4;
        af[mt] = *(const bf16x8*)&As[r * 64 + ((jj ^ (r & 7)) << 3)];
      }
#pragma unroll
      for (int nt = 0; nt < 4; ++nt) {
        int r = wn * 64 + nt * 16 + (lane & 15);
        int jj = (lane >> 4) + ks * 4;
        bg[nt] = *(const bf16x8*)&Bs[r * 64 + ((jj ^ (r & 7)) << 3)];
      }
#pragma unroll
      for (int mt = 0; mt < 4; ++mt)
#pragma unroll
        for (int nt = 0; nt < 4; ++nt)
          acc[mt][nt] = __builtin_amdgcn_mfma_f32_16x16x32_bf16(
              af[mt], bg[nt], acc[mt][nt], 0, 0, 0);
    }
    __syncthreads();
  }

  int s0 = segl[0];
  int s1 = segl[127];
  if (s0 == s1) {  // whole block in one segment: wave-level reduce, 1 atomic/col/wave
    float* o = out + s0 * DOUT;
#pragma unroll
    for (int nt = 0; nt < 4; ++nt) {
      int gc = n0 + wn * 64 + nt * 16 + (lane & 15);
      float s = 16.f * b2[gc];
#pragma unroll
      for (int mt = 0; mt < 4; ++mt)
#pragma unroll
        for (int r = 0; r < 4; ++r) s += acc[mt][nt][r];
      s += __shfl_xor(s, 16);
      s += __shfl_xor(s, 32);
      if ((lane >> 4) == 0) atomicAdd(&o[gc], s);
    }
  } else {  // boundary block: masked reduce per segment present (sorted ids)
    int myseg[16];
#pragma unroll
    for (int mt = 0; mt < 4; ++mt)
#pragma unroll
      for (int r = 0; r < 4; ++r)
        myseg[mt * 4 + r] = segl[wm * 64 + mt * 16 + ((lane >> 4) << 2) + r];
    for (int s = s0; s <= s1; ++s) {
#pragma unroll
      for (int nt = 0; nt < 4; ++nt) {
        int gc = n0 + wn * 64 + nt * 16 + (lane & 15);
        float bias = b2[gc];
        float v = 0.f;
#pragma unroll
        for (int mt = 0; mt < 4; ++mt)
#pragma unroll
          for (int r = 0; r < 4; ++r)
            v += (myseg[mt * 4 + r] == s) ? (acc[mt][nt][r] + bias) : 0.f;
        v += __shfl_xor(v, 16);
        v += __shfl_xor(v, 32);
        if ((lane >> 4) == 0) atomicAdd(&out[s * DOUT + gc], v);
      }
    }
  }
}

extern "C" void kernel_launch(void* const* d_in, const int* in_sizes, int n_in,
                              void* d_out, int out_size, void* d_ws, size_t ws_size,
                              hipStream_t stream) {
  const float* hidden = (const float*)d_in[0];
  const float* W1 = (const float*)d_in[1];
  const float* b1 = (const float*)d_in[2];
  const float* W2 = (const float*)d_in[3];
  const float* b2 = (const float*)d_in[4];
  const int* flat_idx = (const int*)d_in[5];
  const int* seg = (const int*)d_in[6];
  float* out = (float*)d_out;

  unsigned short* W1b = (unsigned short*)d_ws;       // 1024*2048*2 = 4 MiB
  unsigned short* W2b = W1b + (size_t)DMID * H_DIM;  // 256*1024*2  = 512 KiB
  unsigned short* Hbuf = W2b + (size_t)DOUT * DMID;  // 32768*1024*2 = 64 MiB
  unsigned short* Abuf = Hbuf + (size_t)NTOK * DMID; // 32768*2048*2 = 128 MiB

  size_t need_slow = ((size_t)DMID * H_DIM + (size_t)DOUT * DMID + (size_t)NTOK * DMID) * 2;
  size_t need_fast = need_slow + (size_t)NTOK * H_DIM * 2;
  if (ws_size < need_slow) return;
  bool fast = ws_size >= need_fast;

  hipMemsetAsync(d_out, 0, (size_t)NIMG * DOUT * sizeof(float), stream);
  convert_f32_bf16<<<(DMID * H_DIM / 4 + 255) / 256, 256, 0, stream>>>(W1, W1b, DMID * H_DIM / 4);
  convert_f32_bf16<<<(DOUT * DMID / 4 + 255) / 256, 256, 0, stream>>>(W2, W2b, DOUT * DMID / 4);
  if (fast) {
    gather_convert_A<<<NTOK, 256, 0, stream>>>(hidden, flat_idx, Abuf);
    gemm1_mish<true><<<2048, 256, 0, stream>>>(nullptr, Abuf, W1b, b1, nullptr, Hbuf);
  } else {
    gemm1_mish<false><<<2048, 256, 0, stream>>>(hidden, nullptr, W1b, b1, flat_idx, Hbuf);
  }
  gemm2_pool<<<512, 256, 0, stream>>>(Hbuf, W2b, b2, seg, out);
}

// Round 3
// 579.030 us; speedup vs baseline: 1.0685x; 1.0685x over previous
//
#include <hip/hip_runtime.h>

#define H_DIM 2048
#define DMID  1024
#define DOUT  256
#define NTOK  32768
#define NIMG  32

typedef __attribute__((ext_vector_type(8))) __bf16 bf16x8;
typedef __attribute__((ext_vector_type(4))) float f32x4;

__device__ __forceinline__ unsigned f2bf(float f) {
  unsigned u = __builtin_bit_cast(unsigned, f);
  u += 0x7fff + ((u >> 16) & 1);   // RNE
  return u >> 16;
}

// async global->LDS, 16B per lane. LDS dest must be wave-uniform base + lane*16.
__device__ __forceinline__ void async_copy16(const void* gptr, void* lptr) {
  auto g = (const __attribute__((address_space(1))) unsigned int*)(unsigned long long)gptr;
  unsigned loff = (unsigned)(unsigned long long)lptr;
  auto l = (__attribute__((address_space(3))) unsigned int*)loff;
  __builtin_amdgcn_global_load_lds(g, l, 16, 0, 0);
}

__global__ void convert_f32_bf16(const float* __restrict__ src,
                                 unsigned short* __restrict__ dst, int n4) {
  int i = blockIdx.x * blockDim.x + threadIdx.x;
  if (i >= n4) return;
  float4 f = ((const float4*)src)[i];
  ushort4 o;
  o.x = (unsigned short)f2bf(f.x);
  o.y = (unsigned short)f2bf(f.y);
  o.z = (unsigned short)f2bf(f.z);
  o.w = (unsigned short)f2bf(f.w);
  ((ushort4*)dst)[i] = o;
}

// One block per token row: gather via flat_idx + fp32->bf16. 8 elems/thread.
__global__ __launch_bounds__(256) void gather_convert_A(
    const float* __restrict__ hidden, const int* __restrict__ flat_idx,
    unsigned short* __restrict__ Abuf) {
  int row = blockIdx.x;
  int src_row = flat_idx[row];
  const float* src = hidden + (size_t)src_row * H_DIM + threadIdx.x * 8;
  float4 fa = *(const float4*)src;
  float4 fb = *(const float4*)(src + 4);
  uint4 pk;
  pk.x = (f2bf(fa.y) << 16) | f2bf(fa.x);
  pk.y = (f2bf(fa.w) << 16) | f2bf(fa.z);
  pk.z = (f2bf(fb.y) << 16) | f2bf(fb.x);
  pk.w = (f2bf(fb.w) << 16) | f2bf(fb.z);
  *(uint4*)(Abuf + (size_t)row * H_DIM + threadIdx.x * 8) = pk;
}

// C[m,n] = mish(sum_k A[m,k]*W1[n,k] + b1[n]) -> bf16 h
// 2-phase pipelined K-loop: double-buffered LDS; staging for tile t+1 is
// ISSUED before the MFMA work on tile t, so the __syncthreads vmcnt(0) drain
// at the end of the iteration finds the DMA already landed (latency hidden
// under ~250-400cy of ds_read+MFMA) instead of serializing with it.
template <bool PRE>
__global__ __launch_bounds__(256) void gemm1_mish(
    const float* __restrict__ A32, const unsigned short* __restrict__ Abf,
    const unsigned short* __restrict__ B, const float* __restrict__ b1,
    const int* __restrict__ flat_idx, unsigned short* __restrict__ Hout) {
  __shared__ __align__(16) unsigned short As[2][128 * 64];
  __shared__ __align__(16) unsigned short Bs[2][128 * 64];
  __shared__ int rowmap[128];   // dead (DCE'd) for PRE=true

  const int tid = threadIdx.x;
  const int lane = tid & 63;
  const int wave = tid >> 6;
  const int wm = wave >> 1, wn = wave & 1;
  // XCD-clustered decomposition (keeps L2/L3 traffic at the 131MB ideal so the
  // now-faster pipeline can't become L3-BW-bound).
  const int bid = blockIdx.x;
  const int xcd = bid & 7;
  const int j = bid >> 3;
  const int m0 = (xcd * 32 + (j >> 3)) * 128;
  const int n0 = (j & 7) * 128;

  if constexpr (!PRE) {
    if (tid < 128) rowmap[tid] = flat_idx[m0 + tid];
    __syncthreads();
  }

  auto stage = [&](int b, int t) {
    int kk = t * 64;
#pragma unroll
    for (int it = 0; it < 4; ++it) {
      int id = it * 256 + tid;
      int row = id >> 3, c8 = id & 7;
      int gc8 = c8 ^ (row & 7);
      async_copy16(B + (size_t)(n0 + row) * H_DIM + kk + gc8 * 8, &Bs[b][id * 8]);
    }
    if constexpr (PRE) {
#pragma unroll
      for (int it = 0; it < 4; ++it) {
        int id = it * 256 + tid;
        int row = id >> 3, c8 = id & 7;
        int gc8 = c8 ^ (row & 7);
        async_copy16(Abf + (size_t)(m0 + row) * H_DIM + kk + gc8 * 8, &As[b][id * 8]);
      }
    } else {
#pragma unroll
      for (int it = 0; it < 4; ++it) {
        int id = it * 256 + tid;
        int row = id >> 3, c8 = id & 7;
        int gc8 = c8 ^ (row & 7);
        const float* src = A32 + (size_t)rowmap[row] * H_DIM + kk + gc8 * 8;
        float4 fa = *(const float4*)src;
        float4 fb = *(const float4*)(src + 4);
        uint4 pk;
        pk.x = (f2bf(fa.y) << 16) | f2bf(fa.x);
        pk.y = (f2bf(fa.w) << 16) | f2bf(fa.z);
        pk.z = (f2bf(fb.y) << 16) | f2bf(fb.x);
        pk.w = (f2bf(fb.w) << 16) | f2bf(fb.z);
        *(uint4*)&As[b][id * 8] = pk;
      }
    }
  };

  f32x4 acc[4][4];
#pragma unroll
  for (int i = 0; i < 4; i++)
#pragma unroll
    for (int jj = 0; jj < 4; jj++) acc[i][jj] = f32x4{0.f, 0.f, 0.f, 0.f};

  constexpr int NT = H_DIM / 64;  // 32 K-tiles
  stage(0, 0);
  __syncthreads();
  int cur = 0;
  for (int t = 0; t < NT; ++t) {
    if (t + 1 < NT) stage(cur ^ 1, t + 1);  // prefetch next tile (hidden under MFMA)
#pragma unroll
    for (int ks = 0; ks < 2; ++ks) {
      bf16x8 af[4], bg[4];
#pragma unroll
      for (int mt = 0; mt < 4; ++mt) {
        int r = wm * 64 + mt * 16 + (lane & 15);
        int jj = (lane >> 4) + ks * 4;
        af[mt] = *(const bf16x8*)&As[cur][r * 64 + ((jj ^ (r & 7)) << 3)];
      }
#pragma unroll
      for (int nt = 0; nt < 4; ++nt) {
        int r = wn * 64 + nt * 16 + (lane & 15);
        int jj = (lane >> 4) + ks * 4;
        bg[nt] = *(const bf16x8*)&Bs[cur][r * 64 + ((jj ^ (r & 7)) << 3)];
      }
#pragma unroll
      for (int mt = 0; mt < 4; ++mt)
#pragma unroll
        for (int nt = 0; nt < 4; ++nt)
          acc[mt][nt] = __builtin_amdgcn_mfma_f32_16x16x32_bf16(
              af[mt], bg[nt], acc[mt][nt], 0, 0, 0);
    }
    __syncthreads();  // drains vmcnt(0): t+1's DMA, already mostly landed
    cur ^= 1;
  }

#pragma unroll
  for (int nt = 0; nt < 4; ++nt) {
    int gc = n0 + wn * 64 + nt * 16 + (lane & 15);
    float bias = b1[gc];
#pragma unroll
    for (int mt = 0; mt < 4; ++mt) {
#pragma unroll
      for (int r = 0; r < 4; ++r) {
        int grow = m0 + wm * 64 + mt * 16 + ((lane >> 4) << 2) + r;
        float x = acc[mt][nt][r] + bias;
        // mish(x) = x*tanh(softplus(x)) = x*u/(u+2), u = t(t+2), t = e^x
        float t = __expf(x);
        float u = t * (t + 2.f);
        float y = (x < 10.f) ? x * u * __builtin_amdgcn_rcpf(u + 2.f) : x;
        Hout[(size_t)grow * DMID + gc] = (unsigned short)f2bf(y);
      }
    }
  }
}

// out[seg[m], n] += sum_k h[m,k]*W2[n,k] + b2[n]
// Same 2-phase pipelined K-loop.
__global__ __launch_bounds__(256) void gemm2_pool(
    const unsigned short* __restrict__ Hin, const unsigned short* __restrict__ W2b,
    const float* __restrict__ b2, const int* __restrict__ seg,
    float* __restrict__ out) {
  __shared__ __align__(16) unsigned short As[2][128 * 64];
  __shared__ __align__(16) unsigned short Bs[2][128 * 64];
  __shared__ int segl[128];

  const int tid = threadIdx.x;
  const int lane = tid & 63;
  const int wave = tid >> 6;
  const int wm = wave >> 1, wn = wave & 1;
  const int bid = blockIdx.x;
  const int xcd = bid & 7;
  const int j = bid >> 3;
  const int m0 = (xcd * 32 + (j >> 1)) * 128;
  const int n0 = (j & 1) * 128;

  if (tid < 128) segl[tid] = seg[m0 + tid];
  __syncthreads();

  auto stage = [&](int b, int t) {
    int kk = t * 64;
#pragma unroll
    for (int it = 0; it < 4; ++it) {
      int id = it * 256 + tid;
      int row = id >> 3, c8 = id & 7;
      int gc8 = c8 ^ (row & 7);
      async_copy16(Hin + (size_t)(m0 + row) * DMID + kk + gc8 * 8, &As[b][id * 8]);
      async_copy16(W2b + (size_t)(n0 + row) * DMID + kk + gc8 * 8, &Bs[b][id * 8]);
    }
  };

  f32x4 acc[4][4];
#pragma unroll
  for (int i = 0; i < 4; i++)
#pragma unroll
    for (int jj = 0; jj < 4; jj++) acc[i][jj] = f32x4{0.f, 0.f, 0.f, 0.f};

  constexpr int NT = DMID / 64;  // 16 K-tiles
  stage(0, 0);
  __syncthreads();
  int cur = 0;
  for (int t = 0; t < NT; ++t) {
    if (t + 1 < NT) stage(cur ^ 1, t + 1);
#pragma unroll
    for (int ks = 0; ks < 2; ++ks) {
      bf16x8 af[4], bg[4];
#pragma unroll
      for (int mt = 0; mt < 4; ++mt) {
        int r = wm * 64 + mt * 16 + (lane & 15);
        int jj = (lane >> 4) + ks * 4;
        af[mt] = *(const bf16x8*)&As[cur][r * 64 + ((jj ^ (r & 7)) << 3)];
      }
#pragma unroll
      for (int nt = 0; nt < 4; ++nt) {
        int r = wn * 64 + nt * 16 + (lane & 15);
        int jj = (lane >> 4) + ks * 4;
        bg[nt] = *(const bf16x8*)&Bs[cur][r * 64 + ((jj ^ (r & 7)) << 3)];
      }
#pragma unroll
      for (int mt = 0; mt < 4; ++mt)
#pragma unroll
        for (int nt = 0; nt < 4; ++nt)
          acc[mt][nt] = __builtin_amdgcn_mfma_f32_16x16x32_bf16(
              af[mt], bg[nt], acc[mt][nt], 0, 0, 0);
    }
    __syncthreads();
    cur ^= 1;
  }

  int s0 = segl[0];
  int s1 = segl[127];
  if (s0 == s1) {  // whole block in one segment: wave-level reduce, 1 atomic/col/wave
    float* o = out + s0 * DOUT;
#pragma unroll
    for (int nt = 0; nt < 4; ++nt) {
      int gc = n0 + wn * 64 + nt * 16 + (lane & 15);
      float s = 16.f * b2[gc];
#pragma unroll
      for (int mt = 0; mt < 4; ++mt)
#pragma unroll
        for (int r = 0; r < 4; ++r) s += acc[mt][nt][r];
      s += __shfl_xor(s, 16);
      s += __shfl_xor(s, 32);
      if ((lane >> 4) == 0) atomicAdd(&o[gc], s);
    }
  } else {  // boundary block: masked reduce per segment present (sorted ids)
    int myseg[16];
#pragma unroll
    for (int mt = 0; mt < 4; ++mt)
#pragma unroll
      for (int r = 0; r < 4; ++r)
        myseg[mt * 4 + r] = segl[wm * 64 + mt * 16 + ((lane >> 4) << 2) + r];
    for (int s = s0; s <= s1; ++s) {
#pragma unroll
      for (int nt = 0; nt < 4; ++nt) {
        int gc = n0 + wn * 64 + nt * 16 + (lane & 15);
        float bias = b2[gc];
        float v = 0.f;
#pragma unroll
        for (int mt = 0; mt < 4; ++mt)
#pragma unroll
          for (int r = 0; r < 4; ++r)
            v += (myseg[mt * 4 + r] == s) ? (acc[mt][nt][r] + bias) : 0.f;
        v += __shfl_xor(v, 16);
        v += __shfl_xor(v, 32);
        if ((lane >> 4) == 0) atomicAdd(&out[s * DOUT + gc], v);
      }
    }
  }
}

extern "C" void kernel_launch(void* const* d_in, const int* in_sizes, int n_in,
                              void* d_out, int out_size, void* d_ws, size_t ws_size,
                              hipStream_t stream) {
  const float* hidden = (const float*)d_in[0];
  const float* W1 = (const float*)d_in[1];
  const float* b1 = (const float*)d_in[2];
  const float* W2 = (const float*)d_in[3];
  const float* b2 = (const float*)d_in[4];
  const int* flat_idx = (const int*)d_in[5];
  const int* seg = (const int*)d_in[6];
  float* out = (float*)d_out;

  unsigned short* W1b = (unsigned short*)d_ws;       // 1024*2048*2 = 4 MiB
  unsigned short* W2b = W1b + (size_t)DMID * H_DIM;  // 256*1024*2  = 512 KiB
  unsigned short* Hbuf = W2b + (size_t)DOUT * DMID;  // 32768*1024*2 = 64 MiB
  unsigned short* Abuf = Hbuf + (size_t)NTOK * DMID; // 32768*2048*2 = 128 MiB

  size_t need_slow = ((size_t)DMID * H_DIM + (size_t)DOUT * DMID + (size_t)NTOK * DMID) * 2;
  size_t need_fast = need_slow + (size_t)NTOK * H_DIM * 2;
  if (ws_size < need_slow) return;
  bool fast = ws_size >= need_fast;

  hipMemsetAsync(d_out, 0, (size_t)NIMG * DOUT * sizeof(float), stream);
  convert_f32_bf16<<<(DMID * H_DIM / 4 + 255) / 256, 256, 0, stream>>>(W1, W1b, DMID * H_DIM / 4);
  convert_f32_bf16<<<(DOUT * DMID / 4 + 255) / 256, 256, 0, stream>>>(W2, W2b, DOUT * DMID / 4);
  if (fast) {
    gather_convert_A<<<NTOK, 256, 0, stream>>>(hidden, flat_idx, Abuf);
    gemm1_mish<true><<<2048, 256, 0, stream>>>(nullptr, Abuf, W1b, b1, nullptr, Hbuf);
  } else {
    gemm1_mish<false><<<2048, 256, 0, stream>>>(hidden, nullptr, W1b, b1, flat_idx, Hbuf);
  }
  gemm2_pool<<<512, 256, 0, stream>>>(Hbuf, W2b, b2, seg, out);
}

// Round 4
// 572.795 us; speedup vs baseline: 1.0801x; 1.0109x over previous
//
#include <hip/hip_runtime.h>

#define H_DIM 2048
#define DMID  1024
#define DOUT  256
#define NTOK  32768
#define NIMG  32

typedef __attribute__((ext_vector_type(8))) __bf16 bf16x8;
typedef __attribute__((ext_vector_type(4))) float f32x4;

__device__ __forceinline__ unsigned f2bf(float f) {
  unsigned u = __builtin_bit_cast(unsigned, f);
  u += 0x7fff + ((u >> 16) & 1);   // RNE
  return u >> 16;
}

// async global->LDS, 16B per lane. LDS dest must be wave-uniform base + lane*16.
__device__ __forceinline__ void async_copy16(const void* gptr, void* lptr) {
  auto g = (const __attribute__((address_space(1))) unsigned int*)(unsigned long long)gptr;
  unsigned loff = (unsigned)(unsigned long long)lptr;
  auto l = (__attribute__((address_space(3))) unsigned int*)loff;
  __builtin_amdgcn_global_load_lds(g, l, 16, 0, 0);
}

__global__ void convert_f32_bf16(const float* __restrict__ src,
                                 unsigned short* __restrict__ dst, int n4) {
  int i = blockIdx.x * blockDim.x + threadIdx.x;
  if (i >= n4) return;
  float4 f = ((const float4*)src)[i];
  ushort4 o;
  o.x = (unsigned short)f2bf(f.x);
  o.y = (unsigned short)f2bf(f.y);
  o.z = (unsigned short)f2bf(f.z);
  o.w = (unsigned short)f2bf(f.w);
  ((ushort4*)dst)[i] = o;
}

// One block per token row: gather via flat_idx + fp32->bf16. 8 elems/thread.
__global__ __launch_bounds__(256) void gather_convert_A(
    const float* __restrict__ hidden, const int* __restrict__ flat_idx,
    unsigned short* __restrict__ Abuf) {
  int row = blockIdx.x;
  int src_row = flat_idx[row];
  const float* src = hidden + (size_t)src_row * H_DIM + threadIdx.x * 8;
  float4 fa = *(const float4*)src;
  float4 fb = *(const float4*)(src + 4);
  uint4 pk;
  pk.x = (f2bf(fa.y) << 16) | f2bf(fa.x);
  pk.y = (f2bf(fa.w) << 16) | f2bf(fa.z);
  pk.z = (f2bf(fb.y) << 16) | f2bf(fb.x);
  pk.w = (f2bf(fb.w) << 16) | f2bf(fb.z);
  *(uint4*)(Abuf + (size_t)row * H_DIM + threadIdx.x * 8) = pk;
}

// Fully fused: H-tile = mish(A@W1^T + b1) kept on-chip (LDS), then
// out[seg[m],o] += H-tile @ W2slice^T (+ b2 once, gated on n0==0).
// Eliminates the 64MiB Hbuf write+read and the whole gemm2 kernel.
template <bool PRE>
__global__ __launch_bounds__(256, 2) void gemm1_fused(
    const float* __restrict__ A32, const unsigned short* __restrict__ Abf,
    const unsigned short* __restrict__ B, const float* __restrict__ b1,
    const int* __restrict__ flat_idx, const unsigned short* __restrict__ W2b,
    const float* __restrict__ b2, const int* __restrict__ seg,
    float* __restrict__ out) {
  __shared__ __align__(16) unsigned short As[2][128 * 64];  // K-loop A dbuf; epilogue: H 128x128
  __shared__ __align__(16) unsigned short Bs[2][128 * 64];  // K-loop B dbuf; epilogue: W2 128x128 half
  __shared__ int rowmap[128];   // PRE=false only
  __shared__ int segl[128];

  const int tid = threadIdx.x;
  const int lane = tid & 63;
  const int wave = tid >> 6;
  const int wm = wave >> 1, wn = wave & 1;
  // XCD-clustered decomposition: 8 sibling n-blocks of one m-panel adjacent on one XCD.
  const int bid = blockIdx.x;
  const int xcd = bid & 7;
  const int j = bid >> 3;
  const int m0 = (xcd * 32 + (j >> 3)) * 128;
  const int n0 = (j & 7) * 128;

  if constexpr (!PRE) {
    if (tid < 128) rowmap[tid] = flat_idx[m0 + tid];
    __syncthreads();
  }

  auto stage = [&](int b, int t) {
    int kk = t * 64;
#pragma unroll
    for (int it = 0; it < 4; ++it) {
      int id = it * 256 + tid;
      int row = id >> 3, c8 = id & 7;
      int gc8 = c8 ^ (row & 7);
      async_copy16(B + (size_t)(n0 + row) * H_DIM + kk + gc8 * 8, &Bs[b][id * 8]);
    }
    if constexpr (PRE) {
#pragma unroll
      for (int it = 0; it < 4; ++it) {
        int id = it * 256 + tid;
        int row = id >> 3, c8 = id & 7;
        int gc8 = c8 ^ (row & 7);
        async_copy16(Abf + (size_t)(m0 + row) * H_DIM + kk + gc8 * 8, &As[b][id * 8]);
      }
    } else {
#pragma unroll
      for (int it = 0; it < 4; ++it) {
        int id = it * 256 + tid;
        int row = id >> 3, c8 = id & 7;
        int gc8 = c8 ^ (row & 7);
        const float* src = A32 + (size_t)rowmap[row] * H_DIM + kk + gc8 * 8;
        float4 fa = *(const float4*)src;
        float4 fb = *(const float4*)(src + 4);
        uint4 pk;
        pk.x = (f2bf(fa.y) << 16) | f2bf(fa.x);
        pk.y = (f2bf(fa.w) << 16) | f2bf(fa.z);
        pk.z = (f2bf(fb.y) << 16) | f2bf(fb.x);
        pk.w = (f2bf(fb.w) << 16) | f2bf(fb.z);
        *(uint4*)&As[b][id * 8] = pk;
      }
    }
  };

  f32x4 acc[4][4];
#pragma unroll
  for (int i = 0; i < 4; i++)
#pragma unroll
    for (int jj = 0; jj < 4; jj++) acc[i][jj] = f32x4{0.f, 0.f, 0.f, 0.f};

  constexpr int NT = H_DIM / 64;  // 32 K-tiles, 2-phase pipelined
  stage(0, 0);
  __syncthreads();
  int cur = 0;
  for (int t = 0; t < NT; ++t) {
    if (t + 1 < NT) stage(cur ^ 1, t + 1);
#pragma unroll
    for (int ks = 0; ks < 2; ++ks) {
      bf16x8 af[4], bg[4];
#pragma unroll
      for (int mt = 0; mt < 4; ++mt) {
        int r = wm * 64 + mt * 16 + (lane & 15);
        int jj = (lane >> 4) + ks * 4;
        af[mt] = *(const bf16x8*)&As[cur][r * 64 + ((jj ^ (r & 7)) << 3)];
      }
#pragma unroll
      for (int nt = 0; nt < 4; ++nt) {
        int r = wn * 64 + nt * 16 + (lane & 15);
        int jj = (lane >> 4) + ks * 4;
        bg[nt] = *(const bf16x8*)&Bs[cur][r * 64 + ((jj ^ (r & 7)) << 3)];
      }
#pragma unroll
      for (int mt = 0; mt < 4; ++mt)
#pragma unroll
        for (int nt = 0; nt < 4; ++nt)
          acc[mt][nt] = __builtin_amdgcn_mfma_f32_16x16x32_bf16(
              af[mt], bg[nt], acc[mt][nt], 0, 0, 0);
    }
    __syncthreads();
    cur ^= 1;
  }

  // ================= fused epilogue =================
  // Hl: 128(m) x 128(k'=local n) bf16, swizzled [m*128 + ((g^(m&7))<<3) + (k&7)], g=k>>3
  // W2s: 128(o-half) x 128(k') bf16, same swizzle, staged async per 128-o half.
  unsigned short* Hl  = &As[0][0];   // 32 KiB (spans both dbuf halves)
  unsigned short* W2s = &Bs[0][0];   // 32 KiB

  if (tid < 128) segl[tid] = seg[m0 + tid];

  auto stageW2 = [&](int h) {
#pragma unroll
    for (int it = 0; it < 8; ++it) {
      int id = it * 256 + tid;            // 0..2047 granules of 16B
      int row = id >> 4, c16 = id & 15;
      int g = c16 ^ (row & 7);            // involution on low 3 bits
      async_copy16(W2b + (size_t)(h * 128 + row) * DMID + n0 + g * 8, &W2s[id * 8]);
    }
  };
  stageW2(0);

  // mish -> bf16 -> Hl (scalar b16 writes; one-time, 2-4 way conflicts only)
#pragma unroll
  for (int nt = 0; nt < 4; ++nt) {
    int kc = wn * 64 + nt * 16 + (lane & 15);   // local k' in [0,128)
    float bias = b1[n0 + kc];
#pragma unroll
    for (int mt = 0; mt < 4; ++mt) {
#pragma unroll
      for (int r = 0; r < 4; ++r) {
        int ml = wm * 64 + mt * 16 + ((lane >> 4) << 2) + r;
        float x = acc[mt][nt][r] + bias;
        // mish(x) = x*tanh(softplus(x)) = x*u/(u+2), u = t(t+2), t = e^x
        float t = __expf(x);
        float u = t * (t + 2.f);
        float y = (x < 10.f) ? x * u * __builtin_amdgcn_rcpf(u + 2.f) : x;
        int g = kc >> 3;
        Hl[ml * 128 + ((g ^ (ml & 7)) << 3) + (kc & 7)] = (unsigned short)f2bf(y);
      }
    }
  }
  __syncthreads();  // Hl written by all waves; W2 half-0 DMA drained; segl visible

  int s0 = segl[0], s1 = segl[127];
  int myseg[16];
#pragma unroll
  for (int mt = 0; mt < 4; ++mt)
#pragma unroll
    for (int r = 0; r < 4; ++r)
      myseg[mt * 4 + r] = segl[wm * 64 + mt * 16 + ((lane >> 4) << 2) + r];

  for (int h = 0; h < 2; ++h) {
    f32x4 acc2[4][4];
#pragma unroll
    for (int i = 0; i < 4; i++)
#pragma unroll
      for (int jj = 0; jj < 4; jj++) acc2[i][jj] = f32x4{0.f, 0.f, 0.f, 0.f};

#pragma unroll
    for (int ks = 0; ks < 4; ++ks) {
      bf16x8 af[4], bg[4];
#pragma unroll
      for (int mt = 0; mt < 4; ++mt) {
        int m = wm * 64 + mt * 16 + (lane & 15);
        int jj = (lane >> 4) + ks * 4;
        af[mt] = *(const bf16x8*)&Hl[m * 128 + ((jj ^ (m & 7)) << 3)];
      }
#pragma unroll
      for (int ot = 0; ot < 4; ++ot) {
        int o = wn * 64 + ot * 16 + (lane & 15);
        int jj = (lane >> 4) + ks * 4;
        bg[ot] = *(const bf16x8*)&W2s[o * 128 + ((jj ^ (o & 7)) << 3)];
      }
#pragma unroll
      for (int mt = 0; mt < 4; ++mt)
#pragma unroll
        for (int ot = 0; ot < 4; ++ot)
          acc2[mt][ot] = __builtin_amdgcn_mfma_f32_16x16x32_bf16(
              af[mt], bg[ot], acc2[mt][ot], 0, 0, 0);
    }

    if (h == 0) {
      __syncthreads();  // all waves done reading W2s half-0
      stageW2(1);       // prefetch half-1 under the atomics below
    }

    // segment-pooled reduction for this o-half (b2 added once: only n0==0 blocks)
    if (s0 == s1) {
      float* op = out + s0 * DOUT + h * 128;
#pragma unroll
      for (int ot = 0; ot < 4; ++ot) {
        int oc = wn * 64 + ot * 16 + (lane & 15);
        float s = (n0 == 0) ? 16.f * b2[h * 128 + oc] : 0.f;
#pragma unroll
        for (int mt = 0; mt < 4; ++mt)
#pragma unroll
          for (int r = 0; r < 4; ++r) s += acc2[mt][ot][r];
        s += __shfl_xor(s, 16);
        s += __shfl_xor(s, 32);
        if ((lane >> 4) == 0) atomicAdd(&op[oc], s);
      }
    } else {
      for (int sgi = s0; sgi <= s1; ++sgi) {
#pragma unroll
        for (int ot = 0; ot < 4; ++ot) {
          int oc = wn * 64 + ot * 16 + (lane & 15);
          float bias2 = (n0 == 0) ? b2[h * 128 + oc] : 0.f;
          float v = 0.f;
#pragma unroll
          for (int mt = 0; mt < 4; ++mt)
#pragma unroll
            for (int r = 0; r < 4; ++r)
              v += (myseg[mt * 4 + r] == sgi) ? (acc2[mt][ot][r] + bias2) : 0.f;
          v += __shfl_xor(v, 16);
          v += __shfl_xor(v, 32);
          if ((lane >> 4) == 0) atomicAdd(&out[sgi * DOUT + h * 128 + oc], v);
        }
      }
    }

    if (h == 0) __syncthreads();  // W2 half-1 DMA drained before h=1 compute
  }
}

extern "C" void kernel_launch(void* const* d_in, const int* in_sizes, int n_in,
                              void* d_out, int out_size, void* d_ws, size_t ws_size,
                              hipStream_t stream) {
  const float* hidden = (const float*)d_in[0];
  const float* W1 = (const float*)d_in[1];
  const float* b1 = (const float*)d_in[2];
  const float* W2 = (const float*)d_in[3];
  const float* b2 = (const float*)d_in[4];
  const int* flat_idx = (const int*)d_in[5];
  const int* seg = (const int*)d_in[6];
  float* out = (float*)d_out;

  unsigned short* W1b = (unsigned short*)d_ws;       // 1024*2048*2 = 4 MiB
  unsigned short* W2b = W1b + (size_t)DMID * H_DIM;  // 256*1024*2  = 512 KiB
  unsigned short* Abuf = W2b + (size_t)DOUT * DMID;  // 32768*2048*2 = 128 MiB

  size_t need_slow = ((size_t)DMID * H_DIM + (size_t)DOUT * DMID) * 2;
  size_t need_fast = need_slow + (size_t)NTOK * H_DIM * 2;
  if (ws_size < need_slow) return;
  bool fast = ws_size >= need_fast;

  hipMemsetAsync(d_out, 0, (size_t)NIMG * DOUT * sizeof(float), stream);
  convert_f32_bf16<<<(DMID * H_DIM / 4 + 255) / 256, 256, 0, stream>>>(W1, W1b, DMID * H_DIM / 4);
  convert_f32_bf16<<<(DOUT * DMID / 4 + 255) / 256, 256, 0, stream>>>(W2, W2b, DOUT * DMID / 4);
  if (fast) {
    gather_convert_A<<<NTOK, 256, 0, stream>>>(hidden, flat_idx, Abuf);
    gemm1_fused<true><<<2048, 256, 0, stream>>>(nullptr, Abuf, W1b, b1, nullptr,
                                                W2b, b2, seg, out);
  } else {
    gemm1_fused<false><<<2048, 256, 0, stream>>>(hidden, nullptr, W1b, b1, flat_idx,
                                                 W2b, b2, seg, out);
  }
}